// Round 2
// baseline (246.234 us; speedup 1.0000x reference)
//
#include <hip/hip_runtime.h>

typedef __attribute__((ext_vector_type(8))) short short8;
typedef __attribute__((ext_vector_type(4))) float f32x4;
typedef __attribute__((ext_vector_type(2))) int int2v;
typedef __attribute__((ext_vector_type(4))) int int4v;

__device__ __forceinline__ short f2bf(float f) {
  unsigned u = __builtin_bit_cast(unsigned, f);
  u += 0x7fff + ((u >> 16) & 1);  // RNE
  return (short)(u >> 16);
}

__device__ __forceinline__ int pk2bf(float lo, float hi) {
#if defined(__gfx950__) && __has_builtin(__builtin_amdgcn_cvt_pk_bf16_f32)
  typedef __attribute__((ext_vector_type(2))) __bf16 bf16x2;
  bf16x2 v = __builtin_amdgcn_cvt_pk_bf16_f32(lo, hi);
  return __builtin_bit_cast(int, v);
#else
  return (int)(unsigned short)(short)f2bf(lo) | (((int)f2bf(hi)) << 16);
#endif
}

// truncating pack (2 VALU ops; bias cancels through p/l normalization)
__device__ __forceinline__ int pktr(float lo, float hi) {
  return (int)(__builtin_bit_cast(unsigned, lo) >> 16) |
         (int)(__builtin_bit_cast(unsigned, hi) & 0xffff0000u);
}

__device__ __forceinline__ short8 pack8(f32x4 a, f32x4 b) {
  int4v t;
  t.x = pk2bf(a[0], a[1]);
  t.y = pk2bf(a[2], a[3]);
  t.z = pk2bf(b[0], b[1]);
  t.w = pk2bf(b[2], b[3]);
  return __builtin_bit_cast(short8, t);
}

__device__ __forceinline__ float fand(float p, int m) {
  return __builtin_bit_cast(float, __builtin_bit_cast(int, p) & m);
}

__device__ __forceinline__ int bmask(unsigned w, int bit) {
#if __has_builtin(__builtin_amdgcn_sbfe)
  return __builtin_amdgcn_sbfe((int)w, bit, 1);  // 0 or -1
#else
  return ((int)(w << (31 - bit))) >> 31;
#endif
}

__device__ __forceinline__ float fexp2(float x) {
#if __has_builtin(__builtin_amdgcn_exp2f)
  return __builtin_amdgcn_exp2f(x);
#else
  return exp2f(x);
#endif
}

// async global->LDS, 16B per lane; LDS dest = wave-uniform base + lane*16
__device__ __forceinline__ void glds16(const short* g, short* lbase, int lane) {
#if __has_builtin(__builtin_amdgcn_global_load_lds)
  __builtin_amdgcn_global_load_lds(
      (const __attribute__((address_space(1))) unsigned int*)g,
      (__attribute__((address_space(3))) unsigned int*)lbase, 16, 0, 0);
#else
  *(short8*)(lbase + lane * 8) = *(const short8*)g;
#endif
}

// =============== prep: projections + Wo cvt + packed mask table ===============
__global__ __launch_bounds__(256) void prep(const float* __restrict__ q,
                                            const float* __restrict__ k,
                                            const float* __restrict__ v,
                                            const float* __restrict__ Wq,
                                            const float* __restrict__ Wk,
                                            const float* __restrict__ Wv,
                                            const float* __restrict__ Wo,
                                            const int* __restrict__ mask,
                                            short* __restrict__ Qp,
                                            short* __restrict__ Kp,
                                            short* __restrict__ Vtp,
                                            short* __restrict__ Wob,
                                            unsigned* __restrict__ mmod) {
  const int bid = blockIdx.x;
  const int tid = threadIdx.x;

  if (bid >= 4096) {  // ---- mask table ----
    const int mb = bid - 4096;       // (b*32+q64)*16 + kp
    const int kp = mb & 15, bq = mb >> 4;
    const int b_ = bq >> 5, q64 = bq & 31;
    const int wv = tid >> 6, qd = (tid >> 4) & 3, m16_ = tid & 15;
    unsigned d = 0;
#pragma unroll
    for (int hb = 0; hb < 2; ++hb) {
      const int ka = kp * 2 + hb;
#pragma unroll
      for (int r = 0; r < 4; ++r) {
        const int* mr = mask + b_ * 4194304 +
                        (q64 * 64 + wv * 16 + qd * 4 + r) * 2048 + ka * 64 + m16_;
#pragma unroll
        for (int nt = 0; nt < 4; ++nt)
          if (mr[nt * 16] != 0) d |= 1u << (hb * 16 + r * 4 + nt);
      }
    }
    mmod[mb * 256 + tid] = d;
    return;
  }
  if (bid >= 3072) {  // ---- Wo convert ----
    const int i = ((bid - 3072) * 256 + tid) * 4;
    const f32x4 x = *(const f32x4*)&Wo[i];
    int2v o;
    o.x = pk2bf(x[0], x[1]);
    o.y = pk2bf(x[2], x[3]);
    *(int2v*)&Wob[i] = o;
    return;
  }

  // ---- projection: Out = X @ W^T on a 64-row slab ----
  __shared__ short xt[64][72];
  __shared__ short ot[64][72];
  const int mode = bid >> 10;
  const int bt = bid & 1023;
  const float* X;
  const float* W;
  float scale;
  if (mode == 0) { X = q; W = Wq; scale = 0.045084220f; }  // log2(e)/32 folded into Q
  else if (mode == 1) { X = k; W = Wk; scale = 1.0f; }
  else { X = v; W = Wv; scale = 1.0f; }

  const int r0 = bt * 64;
  const int row = tid >> 2, seg = (tid & 3) * 16;
  const f32x4* xs = (const f32x4*)(X + (r0 + row) * 64 + seg);
  const f32x4 x0 = xs[0], x1 = xs[1], x2 = xs[2], x3 = xs[3];
  *(short8*)&xt[row][seg] = pack8(x0, x1);
  *(short8*)&xt[row][seg + 8] = pack8(x2, x3);
  __syncthreads();

  const int lane = tid & 63, wave = tid >> 6;
  const int m16 = lane & 15, quad = lane >> 4;

  const short8 a0 = *(const short8*)&xt[wave * 16 + m16][quad * 8];
  const short8 a1 = *(const short8*)&xt[wave * 16 + m16][32 + quad * 8];

  f32x4 acc[4];
#pragma unroll
  for (int nt = 0; nt < 4; ++nt) {
    const f32x4* wp0 = (const f32x4*)&W[(nt * 16 + m16) * 64 + quad * 8];
    const f32x4* wp1 = (const f32x4*)&W[(nt * 16 + m16) * 64 + 32 + quad * 8];
    const short8 b0 = pack8(wp0[0], wp0[1]);
    const short8 b1 = pack8(wp1[0], wp1[1]);
    f32x4 z = (f32x4){0.f, 0.f, 0.f, 0.f};
    z = __builtin_amdgcn_mfma_f32_16x16x32_bf16(a0, b0, z, 0, 0, 0);
    z = __builtin_amdgcn_mfma_f32_16x16x32_bf16(a1, b1, z, 0, 0, 0);
    acc[nt] = z;
  }

  if (mode != 2) {
#pragma unroll
    for (int nt = 0; nt < 4; ++nt)
#pragma unroll
      for (int r = 0; r < 4; ++r)
        ot[wave * 16 + quad * 4 + r][nt * 16 + m16] = f2bf(acc[nt][r] * scale);
  } else {
    // transposed + sigma-permuted: ot[d][sigma(key)], sigma = 16*quad + 4*r + wave
#pragma unroll
    for (int nt = 0; nt < 4; ++nt)
#pragma unroll
      for (int r = 0; r < 4; ++r)
        ot[nt * 16 + m16][16 * quad + 4 * r + wave] = f2bf(acc[nt][r]);
  }
  __syncthreads();

  const int orow = tid >> 2, opart = tid & 3;
  if (mode != 2) {
    short* dst = (mode == 0 ? Qp : Kp) + (r0 + orow) * 64 + opart * 16;
    *(short8*)&dst[0] = *(const short8*)&ot[orow][opart * 16];
    *(short8*)&dst[8] = *(const short8*)&ot[orow][opart * 16 + 8];
  } else {
    const int bh = r0 >> 11, s0 = r0 & 2047;
    short* dst = Vtp + bh * 131072 + orow * 2048 + s0 + opart * 16;
    *(short8*)&dst[0] = *(const short8*)&ot[orow][opart * 16];
    *(short8*)&dst[8] = *(const short8*)&ot[orow][opart * 16 + 8];
  }
}

// =============== flash128: 128 q-rows/block, FULL K (32 tiles), 2 m-frags/wave ===============
// r13: LDS-traffic attack. r12's counters (MfmaUtil 18, VALUBusy 48) + pipe arithmetic
// showed LDS ~60% busy: each wave read the full 8KB K + 8KB V tile for only 16 q-rows.
// Now each wave owns TWO 16-row m-frags (128 q-rows/block, grid 512): K/V fragments are
// ds_read once and reused across both m-frags -> LDS reads/FLOP halve; staging writes and
// global K/V re-reads also halve. Occupancy drops to 8 waves/CU (2/SIMD), so the vmcnt(0)
// drain is replaced by ledger-counted vmcnt(6) (T4): stage=4 loads + 2 mask loads per kk;
// waits target only the tile being computed; prefetch stays in flight across barriers
// (never drained to 0 in the loop). 2 raw s_barrier per tile (ready / done-reading).
// All memory ops are pinned between asm memory-clobber points, so the per-wave vmcnt
// ledger is exact: steady-state outstanding at tile-A wait = [m(kk),S(2kk),S(2kk+1),
// m(kk+1)] = 12 -> vmcnt(6) drains m(kk)+S(2kk). Peeled last pair: vmcnt(4)/vmcnt(0).
// LDS = 2*8K (K) + 2*8K (V) + 16K (pt, 128 rows XOR-swizzled) = 48KB.
__global__ __launch_bounds__(256) void flash128(const short* __restrict__ Qp,
                                                const short* __restrict__ Kp,
                                                const short* __restrict__ Vt,
                                                const unsigned* __restrict__ mmod,
                                                short* __restrict__ Ob) {
  __shared__ __attribute__((aligned(16))) short kt0[4096];
  __shared__ __attribute__((aligned(16))) short kt1[4096];
  __shared__ __attribute__((aligned(16))) short vt0[4096];
  __shared__ __attribute__((aligned(16))) short vt1[4096];
  __shared__ __attribute__((aligned(16))) short pt[8192];  // 128 rows x 128 B, swizzled
  const int tid = threadIdx.x;
  const int bid = blockIdx.x;
  const int local = bid >> 3;  // XCD-grouping on bid&7
  const int qblk = local & 15;
  const int bh = (bid & 7) * 4 + (local >> 4);
  const int q0 = qblk << 7;
  const int b = bh >> 4;
  const short* Qh = Qp + bh * 131072;
  const short* Kh = Kp + bh * 131072;
  const short* Vh = Vt + bh * 131072;
  const int lane = tid & 63, wave = tid >> 6;
  const int m16 = lane & 15, quad = lane >> 4;
  const int srow = lane >> 3, sj = (lane & 7) ^ srow;
  const int koff = m16 * 128 + ((quad ^ (m16 & 7)) * 16);
  // two q64 mask slabs per block: q64 = qblk*2 + mi; dword stride between slabs = 16*256
  const unsigned* mqa = mmod + ((b * 32 + qblk * 2) * 16) * 256 + tid;

  char* const ptB = (char*)pt;
  int woff[2][4];
  int aoff[2][2];
  const int aswz = (m16 & 7) << 4;
#pragma unroll
  for (int mi = 0; mi < 2; ++mi) {
#pragma unroll
    for (int r = 0; r < 4; ++r)
      woff[mi][r] = (mi * 64 + wave * 16 + quad * 4 + r) * 128 +
                    ((m16 * 8) ^ (((quad * 4 + r) & 7) << 4));
    aoff[mi][0] = (mi * 64 + wave * 16 + m16) * 128 + ((quad * 16) ^ aswz);
    aoff[mi][1] = (mi * 64 + wave * 16 + m16) * 128 + (((quad * 16) + 64) ^ aswz);
  }

  short8 aq[2][2];
#pragma unroll
  for (int mi = 0; mi < 2; ++mi)
#pragma unroll
    for (int h = 0; h < 2; ++h)
      aq[mi][h] = *(const short8*)&Qh[(q0 + mi * 64 + wave * 16 + m16) * 64 +
                                      h * 32 + quad * 8];

  float l[2][4] = {{0.f, 0.f, 0.f, 0.f}, {0.f, 0.f, 0.f, 0.f}};
  f32x4 oacc[2][4];
#pragma unroll
  for (int mi = 0; mi < 2; ++mi)
#pragma unroll
    for (int dt = 0; dt < 4; ++dt) oacc[mi][dt] = (f32x4){0.f, 0.f, 0.f, 0.f};

  // stage 64-key tile ka into (ktb, vtb); 4 glds16 per wave (+4 vmcnt)
  auto stage = [&](short* ktb, short* vtb, int ka) {
#pragma unroll
    for (int t = 0; t < 2; ++t) {
      const int crow = wave * 16 + t * 8;
      glds16(Kh + (ka * 64 + crow + srow) * 64 + sj * 8, ktb + crow * 64, lane);
      glds16(Vh + (crow + srow) * 2048 + ka * 64 + sj * 8, vtb + crow * 64, lane);
    }
  };

  // full tile: S=QK^T (both m-frags share kb reads), masked exp2, P->pt, O+=PV
  auto compute = [&](const short* ktp, const short* vtp, unsigned mwa, unsigned mwb,
                     int bitbase) {
    const char* ktb = (const char*)ktp;
    const char* vtb = (const char*)vtp;
    f32x4 s[2][4];
    __builtin_amdgcn_s_setprio(1);
#pragma unroll
    for (int nt = 0; nt < 4; ++nt) {
      const int o0 = nt * 2048 + koff;
      const short8 kb0 = *(const short8*)(ktb + o0);
      const short8 kb1 = *(const short8*)(ktb + (o0 ^ 64));
#pragma unroll
      for (int mi = 0; mi < 2; ++mi) {
        f32x4 z = (f32x4){0.f, 0.f, 0.f, 0.f};
        z = __builtin_amdgcn_mfma_f32_16x16x32_bf16(aq[mi][0], kb0, z, 0, 0, 0);
        z = __builtin_amdgcn_mfma_f32_16x16x32_bf16(aq[mi][1], kb1, z, 0, 0, 0);
        s[mi][nt] = z;
      }
    }
    __builtin_amdgcn_s_setprio(0);

    // p = exp2(s) & mask-bit; per-lane l; P -> LDS (trunc-pack bf16, sigma cols)
#pragma unroll
    for (int mi = 0; mi < 2; ++mi) {
      const unsigned mw = mi ? mwb : mwa;
#pragma unroll
      for (int r = 0; r < 4; ++r) {
        float p[4];
#pragma unroll
        for (int nt = 0; nt < 4; ++nt)
          p[nt] = fand(fexp2(s[mi][nt][r]), bmask(mw, bitbase + r * 4 + nt));
        l[mi][r] += (p[0] + p[1]) + (p[2] + p[3]);
        int2v pp;
        pp.x = pktr(p[0], p[1]);
        pp.y = pktr(p[2], p[3]);
        *(int2v*)(ptB + woff[mi][r]) = pp;  // wave-private row
      }
    }

    // O += P V (same-wave DS ordering: no barrier for pt); vb reads shared over mi
    short8 ap[2][2];
#pragma unroll
    for (int mi = 0; mi < 2; ++mi) {
      ap[mi][0] = *(const short8*)(ptB + aoff[mi][0]);
      ap[mi][1] = *(const short8*)(ptB + aoff[mi][1]);
    }
    __builtin_amdgcn_s_setprio(1);
#pragma unroll
    for (int dt = 0; dt < 4; ++dt) {
      const int o0 = dt * 2048 + koff;
      const short8 vb0 = *(const short8*)(vtb + o0);
      const short8 vb1 = *(const short8*)(vtb + (o0 ^ 64));
#pragma unroll
      for (int mi = 0; mi < 2; ++mi) {
        f32x4 z = oacc[mi][dt];
        z = __builtin_amdgcn_mfma_f32_16x16x32_bf16(ap[mi][0], vb0, z, 0, 0, 0);
        z = __builtin_amdgcn_mfma_f32_16x16x32_bf16(ap[mi][1], vb1, z, 0, 0, 0);
        oacc[mi][dt] = z;
      }
    }
    __builtin_amdgcn_s_setprio(0);
  };

  // ---- prologue: masks first, then both stages; no drain (first wait covers it) ----
  unsigned mwa = mqa[0];
  unsigned mwb = mqa[4096];
  stage(kt0, vt0, 0);
  stage(kt1, vt1, 1);

  for (int kk = 0; kk < 15; ++kk) {
    const unsigned mwna = mqa[(kk + 1) * 256];
    const unsigned mwnb = mqa[4096 + (kk + 1) * 256];
    // tile A = 2kk (buf0): newer-than-S(2kk) = S(2kk+1)[4] + m(kk+1)[2]
    asm volatile("s_waitcnt vmcnt(6)" ::: "memory");
    __builtin_amdgcn_s_barrier();
    compute(kt0, vt0, mwa, mwb, 0);
    __builtin_amdgcn_s_barrier();  // done reading buf0
    stage(kt0, vt0, 2 * kk + 2);
    // tile B = 2kk+1 (buf1): newer-than-S(2kk+1) = m(kk+1)[2] + S(2kk+2)[4]
    asm volatile("s_waitcnt vmcnt(6)" ::: "memory");
    __builtin_amdgcn_s_barrier();
    compute(kt1, vt1, mwa, mwb, 16);
    __builtin_amdgcn_s_barrier();  // done reading buf1
    stage(kt1, vt1, 2 * kk + 3);
    mwa = mwna;
    mwb = mwnb;
  }
  // peeled kk=15: outstanding [m15(2), S30(4), S31(4)]
  asm volatile("s_waitcnt vmcnt(4)" ::: "memory");
  __builtin_amdgcn_s_barrier();
  compute(kt0, vt0, mwa, mwb, 0);
  asm volatile("s_waitcnt vmcnt(0)" ::: "memory");
  __builtin_amdgcn_s_barrier();
  compute(kt1, vt1, mwa, mwb, 16);

  // l reduction (16-lane groups), normalize, coalesced O store via pt (wave-private rows)
#pragma unroll
  for (int mi = 0; mi < 2; ++mi)
#pragma unroll
    for (int r = 0; r < 4; ++r) {
#pragma unroll
      for (int off = 1; off < 16; off <<= 1) l[mi][r] += __shfl_xor(l[mi][r], off, 16);
      const float inv = 1.0f / l[mi][r];
#pragma unroll
      for (int dt = 0; dt < 4; ++dt)
        *(short*)(ptB + (mi * 64 + wave * 16 + quad * 4 + r) * 128 +
                  ((dt * 32 + m16 * 2) ^ (((quad * 4 + r) & 7) << 4))) =
            f2bf(oacc[mi][dt][r] * inv);
    }

  const int orow = lane >> 2, opart = lane & 3;
  const int oswz = (orow & 7) << 4;
#pragma unroll
  for (int mi = 0; mi < 2; ++mi) {
    const int prow = mi * 64 + wave * 16 + orow;
    short* og = Ob + (bh * 2048 + q0 + prow) * 64 + opart * 16;
    *(short8*)&og[0] = *(const short8*)(ptB + prow * 128 + ((opart * 32) ^ oswz));
    *(short8*)&og[8] = *(const short8*)(ptB + prow * 128 + ((opart * 32 + 16) ^ oswz));
  }
}

// =============== final projection: out = Ob @ Wo^T + bo, 64x128 tiles ===============
__global__ __launch_bounds__(256) void outproj(const short* __restrict__ Ob,
                                               const short* __restrict__ Wob,
                                               const float* __restrict__ bo,
                                               float* __restrict__ out) {
  __shared__ short at[64][72];
  __shared__ short bt[128][72];
  const int tid = threadIdx.x;
  const int bid = blockIdx.x;
  const int ct = bid >> 6, rt = bid & 63;  // ct-major: consecutive bids share Wob slab
  const int r0 = rt * 64, c0 = ct * 128;
  const int lane = tid & 63, wave = tid >> 6;
  const int mr = (wave >> 1) * 32, nc = (wave & 1) * 64;
  const int m16 = lane & 15, quad = lane >> 4;
  const int arow = tid >> 2, apart = tid & 3;
  const int brow = tid >> 1, bhalf = (tid & 1) * 32;

  f32x4 acc[2][4];
#pragma unroll
  for (int mt = 0; mt < 2; ++mt)
#pragma unroll
    for (int nt = 0; nt < 4; ++nt) acc[mt][nt] = (f32x4){0.f, 0.f, 0.f, 0.f};

  for (int kc = 0; kc < 16; ++kc) {
    __syncthreads();
    const short* ag = &Ob[(r0 + arow) * 1024 + kc * 64 + apart * 16];
    const short* bg = &Wob[(c0 + brow) * 1024 + kc * 64 + bhalf];
    *(short8*)&at[arow][apart * 16] = *(const short8*)&ag[0];
    *(short8*)&at[arow][apart * 16 + 8] = *(const short8*)&ag[8];
    *(short8*)&bt[brow][bhalf] = *(const short8*)&bg[0];
    *(short8*)&bt[brow][bhalf + 8] = *(const short8*)&bg[8];
    *(short8*)&bt[brow][bhalf + 16] = *(const short8*)&bg[16];
    *(short8*)&bt[brow][bhalf + 24] = *(const short8*)&bg[24];
    __syncthreads();

#pragma unroll
    for (int kh = 0; kh < 2; ++kh) {
      short8 af[2], bf[4];
#pragma unroll
      for (int i = 0; i < 2; ++i)
        af[i] = *(const short8*)&at[mr + i * 16 + m16][kh * 32 + quad * 8];
#pragma unroll
      for (int j = 0; j < 4; ++j)
        bf[j] = *(const short8*)&bt[nc + j * 16 + m16][kh * 32 + quad * 8];
#pragma unroll
      for (int mt = 0; mt < 2; ++mt)
#pragma unroll
        for (int nt = 0; nt < 4; ++nt)
          acc[mt][nt] = __builtin_amdgcn_mfma_f32_16x16x32_bf16(af[mt], bf[nt], acc[mt][nt], 0, 0, 0);
    }
  }

#pragma unroll
  for (int nt = 0; nt < 4; ++nt) {
    const int col = c0 + nc + nt * 16 + m16;
    const float bias = bo[col];
#pragma unroll
    for (int mt = 0; mt < 2; ++mt)
#pragma unroll
      for (int rr2 = 0; rr2 < 4; ++rr2)
        out[(r0 + mr + mt * 16 + quad * 4 + rr2) * 1024 + col] = acc[mt][nt][rr2] + bias;
  }
}

// ---------------- launch ----------------
extern "C" void kernel_launch(void* const* d_in, const int* in_sizes, int n_in,
                              void* d_out, int out_size, void* d_ws, size_t ws_size,
                              hipStream_t stream) {
  const float* query = (const float*)d_in[0];
  const float* key = (const float*)d_in[1];
  const float* value = (const float*)d_in[2];
  const int* mask = (const int*)d_in[3];
  const float* Wq = (const float*)d_in[4];
  const float* Wk = (const float*)d_in[5];
  const float* Wv = (const float*)d_in[6];
  const float* Wo = (const float*)d_in[7];
  const float* bo = (const float*)d_in[8];
  float* out = (float*)d_out;

  char* ws = (char*)d_ws;
  short* Qp = (short*)(ws);                       // 8 MB
  short* Kp = (short*)(ws + 8388608);             // 8 MB
  short* Vt = (short*)(ws + 16777216);            // 8 MB
  short* Ob = (short*)(ws + 25165824);            // 8 MB (flash output, distinct from Qp)
  short* Wob = (short*)(ws + 41943040);           // 2 MB
  unsigned* mmod = (unsigned*)(ws + 44564480);    // 1 MB

  prep<<<5120, 256, 0, stream>>>(query, key, value, Wq, Wk, Wv, Wo, mask,
                                 Qp, Kp, Vt, Wob, mmod);
  flash128<<<512, 256, 0, stream>>>(Qp, Kp, Vt, mmod, Ob);
  outproj<<<512, 256, 0, stream>>>(Ob, Wob, bo, out);
}

// Round 3
// 233.642 us; speedup vs baseline: 1.0539x; 1.0539x over previous
//
#include <hip/hip_runtime.h>

typedef __attribute__((ext_vector_type(8))) short short8;
typedef __attribute__((ext_vector_type(4))) float f32x4;
typedef __attribute__((ext_vector_type(2))) int int2v;
typedef __attribute__((ext_vector_type(4))) int int4v;

__device__ __forceinline__ short f2bf(float f) {
  unsigned u = __builtin_bit_cast(unsigned, f);
  u += 0x7fff + ((u >> 16) & 1);  // RNE
  return (short)(u >> 16);
}

__device__ __forceinline__ int pk2bf(float lo, float hi) {
#if defined(__gfx950__) && __has_builtin(__builtin_amdgcn_cvt_pk_bf16_f32)
  typedef __attribute__((ext_vector_type(2))) __bf16 bf16x2;
  bf16x2 v = __builtin_amdgcn_cvt_pk_bf16_f32(lo, hi);
  return __builtin_bit_cast(int, v);
#else
  return (int)(unsigned short)(short)f2bf(lo) | (((int)f2bf(hi)) << 16);
#endif
}

// truncating pack (2 VALU ops; bias cancels through p/l normalization)
__device__ __forceinline__ int pktr(float lo, float hi) {
  return (int)(__builtin_bit_cast(unsigned, lo) >> 16) |
         (int)(__builtin_bit_cast(unsigned, hi) & 0xffff0000u);
}

__device__ __forceinline__ short8 pack8(f32x4 a, f32x4 b) {
  int4v t;
  t.x = pk2bf(a[0], a[1]);
  t.y = pk2bf(a[2], a[3]);
  t.z = pk2bf(b[0], b[1]);
  t.w = pk2bf(b[2], b[3]);
  return __builtin_bit_cast(short8, t);
}

__device__ __forceinline__ float fand(float p, int m) {
  return __builtin_bit_cast(float, __builtin_bit_cast(int, p) & m);
}

__device__ __forceinline__ int bmask(unsigned w, int bit) {
#if __has_builtin(__builtin_amdgcn_sbfe)
  return __builtin_amdgcn_sbfe((int)w, bit, 1);  // 0 or -1
#else
  return ((int)(w << (31 - bit))) >> 31;
#endif
}

__device__ __forceinline__ float fexp2(float x) {
#if __has_builtin(__builtin_amdgcn_exp2f)
  return __builtin_amdgcn_exp2f(x);
#else
  return exp2f(x);
#endif
}

// async global->LDS, 16B per lane; LDS dest = wave-uniform base + lane*16
__device__ __forceinline__ void glds16(const short* g, short* lbase, int lane) {
#if __has_builtin(__builtin_amdgcn_global_load_lds)
  __builtin_amdgcn_global_load_lds(
      (const __attribute__((address_space(1))) unsigned int*)g,
      (__attribute__((address_space(3))) unsigned int*)lbase, 16, 0, 0);
#else
  *(short8*)(lbase + lane * 8) = *(const short8*)g;
#endif
}

// =============== prep: projections + Wo cvt + packed mask table ===============
__global__ __launch_bounds__(256) void prep(const float* __restrict__ q,
                                            const float* __restrict__ k,
                                            const float* __restrict__ v,
                                            const float* __restrict__ Wq,
                                            const float* __restrict__ Wk,
                                            const float* __restrict__ Wv,
                                            const float* __restrict__ Wo,
                                            const int* __restrict__ mask,
                                            short* __restrict__ Qp,
                                            short* __restrict__ Kp,
                                            short* __restrict__ Vtp,
                                            short* __restrict__ Wob,
                                            unsigned* __restrict__ mmod) {
  const int bid = blockIdx.x;
  const int tid = threadIdx.x;

  if (bid >= 4096) {  // ---- mask table ----
    const int mb = bid - 4096;       // (b*32+q64)*16 + kp
    const int kp = mb & 15, bq = mb >> 4;
    const int b_ = bq >> 5, q64 = bq & 31;
    const int wv = tid >> 6, qd = (tid >> 4) & 3, m16_ = tid & 15;
    unsigned d = 0;
#pragma unroll
    for (int hb = 0; hb < 2; ++hb) {
      const int ka = kp * 2 + hb;
#pragma unroll
      for (int r = 0; r < 4; ++r) {
        const int* mr = mask + b_ * 4194304 +
                        (q64 * 64 + wv * 16 + qd * 4 + r) * 2048 + ka * 64 + m16_;
#pragma unroll
        for (int nt = 0; nt < 4; ++nt)
          if (mr[nt * 16] != 0) d |= 1u << (hb * 16 + r * 4 + nt);
      }
    }
    mmod[mb * 256 + tid] = d;
    return;
  }
  if (bid >= 3072) {  // ---- Wo convert ----
    const int i = ((bid - 3072) * 256 + tid) * 4;
    const f32x4 x = *(const f32x4*)&Wo[i];
    int2v o;
    o.x = pk2bf(x[0], x[1]);
    o.y = pk2bf(x[2], x[3]);
    *(int2v*)&Wob[i] = o;
    return;
  }

  // ---- projection: Out = X @ W^T on a 64-row slab ----
  __shared__ short xt[64][72];
  __shared__ short ot[64][72];
  const int mode = bid >> 10;
  const int bt = bid & 1023;
  const float* X;
  const float* W;
  float scale;
  if (mode == 0) { X = q; W = Wq; scale = 0.045084220f; }  // log2(e)/32 folded into Q
  else if (mode == 1) { X = k; W = Wk; scale = 1.0f; }
  else { X = v; W = Wv; scale = 1.0f; }

  const int r0 = bt * 64;
  const int row = tid >> 2, seg = (tid & 3) * 16;
  const f32x4* xs = (const f32x4*)(X + (r0 + row) * 64 + seg);
  const f32x4 x0 = xs[0], x1 = xs[1], x2 = xs[2], x3 = xs[3];
  *(short8*)&xt[row][seg] = pack8(x0, x1);
  *(short8*)&xt[row][seg + 8] = pack8(x2, x3);
  __syncthreads();

  const int lane = tid & 63, wave = tid >> 6;
  const int m16 = lane & 15, quad = lane >> 4;

  const short8 a0 = *(const short8*)&xt[wave * 16 + m16][quad * 8];
  const short8 a1 = *(const short8*)&xt[wave * 16 + m16][32 + quad * 8];

  f32x4 acc[4];
#pragma unroll
  for (int nt = 0; nt < 4; ++nt) {
    const f32x4* wp0 = (const f32x4*)&W[(nt * 16 + m16) * 64 + quad * 8];
    const f32x4* wp1 = (const f32x4*)&W[(nt * 16 + m16) * 64 + 32 + quad * 8];
    const short8 b0 = pack8(wp0[0], wp0[1]);
    const short8 b1 = pack8(wp1[0], wp1[1]);
    f32x4 z = (f32x4){0.f, 0.f, 0.f, 0.f};
    z = __builtin_amdgcn_mfma_f32_16x16x32_bf16(a0, b0, z, 0, 0, 0);
    z = __builtin_amdgcn_mfma_f32_16x16x32_bf16(a1, b1, z, 0, 0, 0);
    acc[nt] = z;
  }

  if (mode != 2) {
#pragma unroll
    for (int nt = 0; nt < 4; ++nt)
#pragma unroll
      for (int r = 0; r < 4; ++r)
        ot[wave * 16 + quad * 4 + r][nt * 16 + m16] = f2bf(acc[nt][r] * scale);
  } else {
    // transposed + sigma-permuted: ot[d][sigma(key)], sigma = 16*quad + 4*r + wave
#pragma unroll
    for (int nt = 0; nt < 4; ++nt)
#pragma unroll
      for (int r = 0; r < 4; ++r)
        ot[nt * 16 + m16][16 * quad + 4 * r + wave] = f2bf(acc[nt][r]);
  }
  __syncthreads();

  const int orow = tid >> 2, opart = tid & 3;
  if (mode != 2) {
    short* dst = (mode == 0 ? Qp : Kp) + (r0 + orow) * 64 + opart * 16;
    *(short8*)&dst[0] = *(const short8*)&ot[orow][opart * 16];
    *(short8*)&dst[8] = *(const short8*)&ot[orow][opart * 16 + 8];
  } else {
    const int bh = r0 >> 11, s0 = r0 & 2047;
    short* dst = Vtp + bh * 131072 + orow * 2048 + s0 + opart * 16;
    *(short8*)&dst[0] = *(const short8*)&ot[orow][opart * 16];
    *(short8*)&dst[8] = *(const short8*)&ot[orow][opart * 16 + 8];
  }
}

// =============== flash64s: 64 q-rows, key/d-split across waves ===============
// r14: r13's LDS-byte cut WITHOUT the occupancy cut. Block = 64 q-rows (grid 1024,
// 4 blocks/CU, 16 waves/CU as r12); wave w = (qh=w>>1, kh=w&1). QK^T: wave computes
// the 32q x 32k S-quadrant (reads HALF of K = 4KB); P goes through pt (sigma cols,
// quadrant store at col 4*m16 + kh*2 + nt'); PV: wave computes the 32q x 32d
// O-quadrant (reads ALL P = 4KB + HALF of V = 4KB). Per-wave LDS reads 18KB -> 12KB
// at IDENTICAL per-wave MFMA/exp counts to r12 (r13 lesson: cut bytes/wave, not
// waves). P is now cross-wave: 3 barriers per half-tile (ready / P-ready / done),
// lgkmcnt(0)-only (no vmcnt drain). Counted-vmcnt ledger as r13: steady vmcnt(6),
// peel (4)/(0). l combined across kh-halves once in the epilogue via kt0 scratch.
// LDS = 2*8K (K) + 2*8K (V) + 8K (pt) = 40960 -> 4 blocks/CU.
__global__ __launch_bounds__(256) void flash64s(const short* __restrict__ Qp,
                                                const short* __restrict__ Kp,
                                                const short* __restrict__ Vt,
                                                const unsigned* __restrict__ mmod,
                                                short* __restrict__ Ob) {
  __shared__ __attribute__((aligned(16))) short kt0[4096];
  __shared__ __attribute__((aligned(16))) short kt1[4096];
  __shared__ __attribute__((aligned(16))) short vt0[4096];
  __shared__ __attribute__((aligned(16))) short vt1[4096];
  __shared__ __attribute__((aligned(16))) short pt[4096];  // 64 x 128B, XOR-swizzled
  const int tid = threadIdx.x;
  const int bid = blockIdx.x;
  const int local = bid >> 3;  // XCD-grouping on bid&7
  const int qblk = local & 31;
  const int bh = (bid & 7) * 4 + (local >> 5);
  const int q0 = qblk << 6;
  const int b = bh >> 4;
  const short* Qh = Qp + bh * 131072;
  const short* Kh = Kp + bh * 131072;
  const short* Vh = Vt + bh * 131072;
  const int lane = tid & 63, wave = tid >> 6;
  const int qh = wave >> 1, kh = wave & 1;  // kh doubles as the d-half in PV
  const int m16 = lane & 15, quad = lane >> 4;
  const int srow = lane >> 3, sj = (lane & 7) ^ srow;
  const int koff = m16 * 128 + ((quad ^ (m16 & 7)) * 16);
  const int bbk = kh * 2;
  // mask dwords: lane needs table-entry tid' = (qh*2+mt)*64 + quad*16 + m16
  const unsigned* mqp = mmod + ((b * 32 + qblk) * 16) * 256 + qh * 128 + quad * 16 + m16;

  char* const ptB = (char*)pt;
  // P-write offsets: row = qh*32+mt*16+quad*4+r, col bytes m16*8 + kh*4 (2 bf16)
  int pwoff[2][4];
#pragma unroll
  for (int mt = 0; mt < 2; ++mt)
#pragma unroll
    for (int r = 0; r < 4; ++r) {
      const int row = qh * 32 + mt * 16 + quad * 4 + r;
      pwoff[mt][r] = row * 128 + ((m16 * 8 + kh * 4) ^ ((row & 7) << 4));
    }
  // P A-frag read offsets: row = qh*32+mt*16+m16, sigma halves h*64
  int paoff[2][2];
#pragma unroll
  for (int mt = 0; mt < 2; ++mt)
#pragma unroll
    for (int h = 0; h < 2; ++h)
      paoff[mt][h] = (qh * 32 + mt * 16 + m16) * 128 +
                     ((quad * 16 + h * 64) ^ ((m16 & 7) << 4));

  short8 aq[2][2];
#pragma unroll
  for (int mt = 0; mt < 2; ++mt)
#pragma unroll
    for (int h = 0; h < 2; ++h)
      aq[mt][h] = *(const short8*)&Qh[(q0 + qh * 32 + mt * 16 + m16) * 64 +
                                      h * 32 + quad * 8];

  float l[2][4] = {{0.f, 0.f, 0.f, 0.f}, {0.f, 0.f, 0.f, 0.f}};
  f32x4 oacc[2][2];
#pragma unroll
  for (int mt = 0; mt < 2; ++mt)
#pragma unroll
    for (int dt = 0; dt < 2; ++dt) oacc[mt][dt] = (f32x4){0.f, 0.f, 0.f, 0.f};

  // stage 64-key tile ka into (ktb, vtb); 4 glds16 per wave (+4 vmcnt)
  auto stage = [&](short* ktb, short* vtb, int ka) {
#pragma unroll
    for (int t = 0; t < 2; ++t) {
      const int crow = wave * 16 + t * 8;
      glds16(Kh + (ka * 64 + crow + srow) * 64 + sj * 8, ktb + crow * 64, lane);
      glds16(Vh + (crow + srow) * 2048 + ka * 64 + sj * 8, vtb + crow * 64, lane);
    }
  };

  // QK quadrant + masked exp2 + P-store (reads kt half; writes pt quadrant)
  auto qk_phase = [&](const short* ktp, unsigned mw0, unsigned mw1, int bb) {
    const char* ktb = (const char*)ktp;
    f32x4 s[2][2];
    __builtin_amdgcn_s_setprio(1);
#pragma unroll
    for (int nt = 0; nt < 2; ++nt) {
      const int o0 = (kh * 2 + nt) * 2048 + koff;
      const short8 kb0 = *(const short8*)(ktb + o0);
      const short8 kb1 = *(const short8*)(ktb + (o0 ^ 64));
#pragma unroll
      for (int mt = 0; mt < 2; ++mt) {
        f32x4 z = (f32x4){0.f, 0.f, 0.f, 0.f};
        z = __builtin_amdgcn_mfma_f32_16x16x32_bf16(aq[mt][0], kb0, z, 0, 0, 0);
        z = __builtin_amdgcn_mfma_f32_16x16x32_bf16(aq[mt][1], kb1, z, 0, 0, 0);
        s[mt][nt] = z;
      }
    }
    __builtin_amdgcn_s_setprio(0);
#pragma unroll
    for (int mt = 0; mt < 2; ++mt) {
      const unsigned mw = mt ? mw1 : mw0;
#pragma unroll
      for (int r = 0; r < 4; ++r) {
        const float p0 = fand(fexp2(s[0 + mt][0][r]), bmask(mw, bb + bbk + r * 4));
        const float p1 = fand(fexp2(s[0 + mt][1][r]), bmask(mw, bb + bbk + r * 4 + 1));
        l[mt][r] += p0 + p1;
        *(int*)(ptB + pwoff[mt][r]) = pktr(p0, p1);
      }
    }
  };

  // PV: O quadrant += P(all keys) * V(d-half)
  auto pv_phase = [&](const short* vtp) {
    const char* vtb = (const char*)vtp;
    short8 ap[2][2];
#pragma unroll
    for (int mt = 0; mt < 2; ++mt) {
      ap[mt][0] = *(const short8*)(ptB + paoff[mt][0]);
      ap[mt][1] = *(const short8*)(ptB + paoff[mt][1]);
    }
    __builtin_amdgcn_s_setprio(1);
#pragma unroll
    for (int dt = 0; dt < 2; ++dt) {
      const int o0 = (kh * 2 + dt) * 2048 + koff;
      const short8 vb0 = *(const short8*)(vtb + o0);
      const short8 vb1 = *(const short8*)(vtb + (o0 ^ 64));
#pragma unroll
      for (int mt = 0; mt < 2; ++mt) {
        f32x4 z = oacc[mt][dt];
        z = __builtin_amdgcn_mfma_f32_16x16x32_bf16(ap[mt][0], vb0, z, 0, 0, 0);
        z = __builtin_amdgcn_mfma_f32_16x16x32_bf16(ap[mt][1], vb1, z, 0, 0, 0);
        oacc[mt][dt] = z;
      }
    }
    __builtin_amdgcn_s_setprio(0);
  };

  // ---- prologue: masks for kk=0, then both stages; first wait covers the drain ----
  unsigned mw0 = mqp[0];
  unsigned mw1 = mqp[64];
  stage(kt0, vt0, 0);
  stage(kt1, vt1, 1);

  for (int kk = 0; kk < 15; ++kk) {
    const unsigned mwn0 = mqp[(kk + 1) * 256];
    const unsigned mwn1 = mqp[(kk + 1) * 256 + 64];
    // tile A = 2kk (buf0); newer-than-S(2kk) = S(2kk+1)[4] + M(kk+1)[2] -> vmcnt(6)
    asm volatile("s_waitcnt vmcnt(6)" ::: "memory");
    __builtin_amdgcn_s_barrier();
    qk_phase(kt0, mw0, mw1, 0);
    asm volatile("s_waitcnt lgkmcnt(0)" ::: "memory");
    __builtin_amdgcn_s_barrier();  // P ready (cross-wave)
    pv_phase(vt0);
    asm volatile("s_waitcnt lgkmcnt(0)" ::: "memory");
    __builtin_amdgcn_s_barrier();  // done reading buf0 + pt
    stage(kt0, vt0, 2 * kk + 2);
    // tile B = 2kk+1 (buf1); newer-than-S(2kk+1) = M(kk+1)[2] + S(2kk+2)[4] -> vmcnt(6)
    asm volatile("s_waitcnt vmcnt(6)" ::: "memory");
    __builtin_amdgcn_s_barrier();
    qk_phase(kt1, mw0, mw1, 16);
    asm volatile("s_waitcnt lgkmcnt(0)" ::: "memory");
    __builtin_amdgcn_s_barrier();  // P ready
    pv_phase(vt1);
    asm volatile("s_waitcnt lgkmcnt(0)" ::: "memory");
    __builtin_amdgcn_s_barrier();  // done reading buf1 + pt
    stage(kt1, vt1, 2 * kk + 3);
    mw0 = mwn0;
    mw1 = mwn1;
  }
  // peeled kk=15: outstanding [M15(2), S30(4), S31(4)]
  asm volatile("s_waitcnt vmcnt(4)" ::: "memory");
  __builtin_amdgcn_s_barrier();
  qk_phase(kt0, mw0, mw1, 0);
  asm volatile("s_waitcnt lgkmcnt(0)" ::: "memory");
  __builtin_amdgcn_s_barrier();
  pv_phase(vt0);
  asm volatile("s_waitcnt lgkmcnt(0) vmcnt(0)" ::: "memory");
  __builtin_amdgcn_s_barrier();  // pt safe for next P-write AND buf1 staged
  qk_phase(kt1, mw0, mw1, 16);
  asm volatile("s_waitcnt lgkmcnt(0)" ::: "memory");
  __builtin_amdgcn_s_barrier();
  pv_phase(vt1);

  // ---- epilogue ----
  // per-wave l partials (own kh-half): reduce over m16 within 16-lane groups
#pragma unroll
  for (int mt = 0; mt < 2; ++mt)
#pragma unroll
    for (int r = 0; r < 4; ++r)
#pragma unroll
      for (int off = 1; off < 16; off <<= 1)
        l[mt][r] += __shfl_xor(l[mt][r], off, 16);

  // exchange partials across kh-halves via kt0 scratch (once)
  float* lx = (float*)kt0;
  if (m16 == 0) {
#pragma unroll
    for (int mt = 0; mt < 2; ++mt)
#pragma unroll
      for (int r = 0; r < 4; ++r)
        lx[kh * 64 + qh * 32 + mt * 16 + quad * 4 + r] = l[mt][r];
  }
  asm volatile("s_waitcnt lgkmcnt(0)" ::: "memory");
  __builtin_amdgcn_s_barrier();  // also separates final PV reads from pt O-writes

  // normalize, write O quadrant (bf16) into pt (swizzled)
#pragma unroll
  for (int mt = 0; mt < 2; ++mt)
#pragma unroll
    for (int r = 0; r < 4; ++r) {
      const int row = qh * 32 + mt * 16 + quad * 4 + r;
      const float lt = l[mt][r] + lx[(kh ^ 1) * 64 + row];
      const float inv = 1.0f / lt;
#pragma unroll
      for (int dt = 0; dt < 2; ++dt)
        *(short*)(ptB + row * 128 +
                  ((kh * 64 + dt * 32 + m16 * 2) ^ ((row & 7) << 4))) =
            f2bf(oacc[mt][dt][r] * inv);
    }
  asm volatile("s_waitcnt lgkmcnt(0)" ::: "memory");
  __builtin_amdgcn_s_barrier();

  // coalesced O store (rows partitioned across waves)
  const int orow = lane >> 2, opart = lane & 3;
  const int prow = wave * 16 + orow;
  const int oswz = (orow & 7) << 4;
  short* og = Ob + (bh * 2048 + q0 + prow) * 64 + opart * 16;
  *(short8*)&og[0] = *(const short8*)(ptB + prow * 128 + ((opart * 32) ^ oswz));
  *(short8*)&og[8] = *(const short8*)(ptB + prow * 128 + ((opart * 32 + 16) ^ oswz));
}

// =============== final projection: out = Ob @ Wo^T + bo, 64x128 tiles ===============
__global__ __launch_bounds__(256) void outproj(const short* __restrict__ Ob,
                                               const short* __restrict__ Wob,
                                               const float* __restrict__ bo,
                                               float* __restrict__ out) {
  __shared__ short at[64][72];
  __shared__ short bt[128][72];
  const int tid = threadIdx.x;
  const int bid = blockIdx.x;
  const int ct = bid >> 6, rt = bid & 63;  // ct-major: consecutive bids share Wob slab
  const int r0 = rt * 64, c0 = ct * 128;
  const int lane = tid & 63, wave = tid >> 6;
  const int mr = (wave >> 1) * 32, nc = (wave & 1) * 64;
  const int m16 = lane & 15, quad = lane >> 4;
  const int arow = tid >> 2, apart = tid & 3;
  const int brow = tid >> 1, bhalf = (tid & 1) * 32;

  f32x4 acc[2][4];
#pragma unroll
  for (int mt = 0; mt < 2; ++mt)
#pragma unroll
    for (int nt = 0; nt < 4; ++nt) acc[mt][nt] = (f32x4){0.f, 0.f, 0.f, 0.f};

  for (int kc = 0; kc < 16; ++kc) {
    __syncthreads();
    const short* ag = &Ob[(r0 + arow) * 1024 + kc * 64 + apart * 16];
    const short* bg = &Wob[(c0 + brow) * 1024 + kc * 64 + bhalf];
    *(short8*)&at[arow][apart * 16] = *(const short8*)&ag[0];
    *(short8*)&at[arow][apart * 16 + 8] = *(const short8*)&ag[8];
    *(short8*)&bt[brow][bhalf] = *(const short8*)&bg[0];
    *(short8*)&bt[brow][bhalf + 8] = *(const short8*)&bg[8];
    *(short8*)&bt[brow][bhalf + 16] = *(const short8*)&bg[16];
    *(short8*)&bt[brow][bhalf + 24] = *(const short8*)&bg[24];
    __syncthreads();

#pragma unroll
    for (int kh = 0; kh < 2; ++kh) {
      short8 af[2], bf[4];
#pragma unroll
      for (int i = 0; i < 2; ++i)
        af[i] = *(const short8*)&at[mr + i * 16 + m16][kh * 32 + quad * 8];
#pragma unroll
      for (int j = 0; j < 4; ++j)
        bf[j] = *(const short8*)&bt[nc + j * 16 + m16][kh * 32 + quad * 8];
#pragma unroll
      for (int mt = 0; mt < 2; ++mt)
#pragma unroll
        for (int nt = 0; nt < 4; ++nt)
          acc[mt][nt] = __builtin_amdgcn_mfma_f32_16x16x32_bf16(af[mt], bf[nt], acc[mt][nt], 0, 0, 0);
    }
  }

#pragma unroll
  for (int nt = 0; nt < 4; ++nt) {
    const int col = c0 + nc + nt * 16 + m16;
    const float bias = bo[col];
#pragma unroll
    for (int mt = 0; mt < 2; ++mt)
#pragma unroll
      for (int rr2 = 0; rr2 < 4; ++rr2)
        out[(r0 + mr + mt * 16 + quad * 4 + rr2) * 1024 + col] = acc[mt][nt][rr2] + bias;
  }
}

// ---------------- launch ----------------
extern "C" void kernel_launch(void* const* d_in, const int* in_sizes, int n_in,
                              void* d_out, int out_size, void* d_ws, size_t ws_size,
                              hipStream_t stream) {
  const float* query = (const float*)d_in[0];
  const float* key = (const float*)d_in[1];
  const float* value = (const float*)d_in[2];
  const int* mask = (const int*)d_in[3];
  const float* Wq = (const float*)d_in[4];
  const float* Wk = (const float*)d_in[5];
  const float* Wv = (const float*)d_in[6];
  const float* Wo = (const float*)d_in[7];
  const float* bo = (const float*)d_in[8];
  float* out = (float*)d_out;

  char* ws = (char*)d_ws;
  short* Qp = (short*)(ws);                       // 8 MB
  short* Kp = (short*)(ws + 8388608);             // 8 MB
  short* Vt = (short*)(ws + 16777216);            // 8 MB
  short* Ob = (short*)(ws + 25165824);            // 8 MB (flash output, distinct from Qp)
  short* Wob = (short*)(ws + 41943040);           // 2 MB
  unsigned* mmod = (unsigned*)(ws + 44564480);    // 1 MB

  prep<<<5120, 256, 0, stream>>>(query, key, value, Wq, Wk, Wv, Wo, mask,
                                 Qp, Kp, Vt, Wob, mmod);
  flash64s<<<1024, 256, 0, stream>>>(Qp, Kp, Vt, mmod, Ob);
  outproj<<<512, 256, 0, stream>>>(Ob, Wob, bo, out);
}

// Round 4
// 220.243 us; speedup vs baseline: 1.1180x; 1.0608x over previous
//
#include <hip/hip_runtime.h>

typedef __attribute__((ext_vector_type(8))) short short8;
typedef __attribute__((ext_vector_type(4))) float f32x4;
typedef __attribute__((ext_vector_type(2))) int int2v;
typedef __attribute__((ext_vector_type(4))) int int4v;

__device__ __forceinline__ short f2bf(float f) {
  unsigned u = __builtin_bit_cast(unsigned, f);
  u += 0x7fff + ((u >> 16) & 1);  // RNE
  return (short)(u >> 16);
}

__device__ __forceinline__ int pk2bf(float lo, float hi) {
#if defined(__gfx950__) && __has_builtin(__builtin_amdgcn_cvt_pk_bf16_f32)
  typedef __attribute__((ext_vector_type(2))) __bf16 bf16x2;
  bf16x2 v = __builtin_amdgcn_cvt_pk_bf16_f32(lo, hi);
  return __builtin_bit_cast(int, v);
#else
  return (int)(unsigned short)(short)f2bf(lo) | (((int)f2bf(hi)) << 16);
#endif
}

// truncating pack (2 VALU ops; bias cancels through p/l normalization)
__device__ __forceinline__ int pktr(float lo, float hi) {
  return (int)(__builtin_bit_cast(unsigned, lo) >> 16) |
         (int)(__builtin_bit_cast(unsigned, hi) & 0xffff0000u);
}

__device__ __forceinline__ short8 pack8(f32x4 a, f32x4 b) {
  int4v t;
  t.x = pk2bf(a[0], a[1]);
  t.y = pk2bf(a[2], a[3]);
  t.z = pk2bf(b[0], b[1]);
  t.w = pk2bf(b[2], b[3]);
  return __builtin_bit_cast(short8, t);
}

__device__ __forceinline__ float fand(float p, int m) {
  return __builtin_bit_cast(float, __builtin_bit_cast(int, p) & m);
}

__device__ __forceinline__ int bmask(unsigned w, int bit) {
#if __has_builtin(__builtin_amdgcn_sbfe)
  return __builtin_amdgcn_sbfe((int)w, bit, 1);  // 0 or -1
#else
  return ((int)(w << (31 - bit))) >> 31;
#endif
}

__device__ __forceinline__ float fexp2(float x) {
#if __has_builtin(__builtin_amdgcn_exp2f)
  return __builtin_amdgcn_exp2f(x);
#else
  return exp2f(x);
#endif
}

// async global->LDS, 16B per lane; LDS dest = wave-uniform base + lane*16
__device__ __forceinline__ void glds16(const short* g, short* lbase, int lane) {
#if __has_builtin(__builtin_amdgcn_global_load_lds)
  __builtin_amdgcn_global_load_lds(
      (const __attribute__((address_space(1))) unsigned int*)g,
      (__attribute__((address_space(3))) unsigned int*)lbase, 16, 0, 0);
#else
  *(short8*)(lbase + lane * 8) = *(const short8*)g;
#endif
}

// =============== prep: projections + Wo cvt + packed mask table ===============
// r15: mask-table bit layout and V column permutation sigma' changed to match the
// in-register-P flash (see flash64r). sigma'(grp*16 + qk*4 + r) = qk*8 + (grp&1)*4
// + r + (grp>>1)*32, so a lane's swapped-QK outputs are verbatim PV A-fragments.
__global__ __launch_bounds__(256) void prep(const float* __restrict__ q,
                                            const float* __restrict__ k,
                                            const float* __restrict__ v,
                                            const float* __restrict__ Wq,
                                            const float* __restrict__ Wk,
                                            const float* __restrict__ Wv,
                                            const float* __restrict__ Wo,
                                            const int* __restrict__ mask,
                                            short* __restrict__ Qp,
                                            short* __restrict__ Kp,
                                            short* __restrict__ Vtp,
                                            short* __restrict__ Wob,
                                            unsigned* __restrict__ mmod) {
  const int bid = blockIdx.x;
  const int tid = threadIdx.x;

  if (bid >= 4096) {  // ---- mask table (in-reg-P layout) ----
    const int mb = bid - 4096;       // (b*32+q64)*16 + kp
    const int kp = mb & 15, bq = mb >> 4;
    const int b_ = bq >> 5, q64 = bq & 31;
    const int wv = tid >> 6, qd = (tid >> 4) & 3, m16_ = tid & 15;
    // bit[hb*16+grp*4+r] = mask[q64*64 + wv*16 + m16_][(kp*2+hb)*64 + grp*16 + qd*4 + r]
    unsigned d = 0;
#pragma unroll
    for (int hb = 0; hb < 2; ++hb) {
      const int* mr = mask + b_ * 4194304 + (q64 * 64 + wv * 16 + m16_) * 2048 +
                      (kp * 2 + hb) * 64 + qd * 4;
#pragma unroll
      for (int grp = 0; grp < 4; ++grp)
#pragma unroll
        for (int r = 0; r < 4; ++r)
          if (mr[grp * 16 + r] != 0) d |= 1u << (hb * 16 + grp * 4 + r);
    }
    mmod[mb * 256 + tid] = d;
    return;
  }
  if (bid >= 3072) {  // ---- Wo convert ----
    const int i = ((bid - 3072) * 256 + tid) * 4;
    const f32x4 x = *(const f32x4*)&Wo[i];
    int2v o;
    o.x = pk2bf(x[0], x[1]);
    o.y = pk2bf(x[2], x[3]);
    *(int2v*)&Wob[i] = o;
    return;
  }

  // ---- projection: Out = X @ W^T on a 64-row slab ----
  __shared__ short xt[64][72];
  __shared__ short ot[64][72];
  const int mode = bid >> 10;
  const int bt = bid & 1023;
  const float* X;
  const float* W;
  float scale;
  if (mode == 0) { X = q; W = Wq; scale = 0.045084220f; }  // log2(e)/32 folded into Q
  else if (mode == 1) { X = k; W = Wk; scale = 1.0f; }
  else { X = v; W = Wv; scale = 1.0f; }

  const int r0 = bt * 64;
  const int row = tid >> 2, seg = (tid & 3) * 16;
  const f32x4* xs = (const f32x4*)(X + (r0 + row) * 64 + seg);
  const f32x4 x0 = xs[0], x1 = xs[1], x2 = xs[2], x3 = xs[3];
  *(short8*)&xt[row][seg] = pack8(x0, x1);
  *(short8*)&xt[row][seg + 8] = pack8(x2, x3);
  __syncthreads();

  const int lane = tid & 63, wave = tid >> 6;
  const int m16 = lane & 15, quad = lane >> 4;

  const short8 a0 = *(const short8*)&xt[wave * 16 + m16][quad * 8];
  const short8 a1 = *(const short8*)&xt[wave * 16 + m16][32 + quad * 8];

  f32x4 acc[4];
#pragma unroll
  for (int nt = 0; nt < 4; ++nt) {
    const f32x4* wp0 = (const f32x4*)&W[(nt * 16 + m16) * 64 + quad * 8];
    const f32x4* wp1 = (const f32x4*)&W[(nt * 16 + m16) * 64 + 32 + quad * 8];
    const short8 b0 = pack8(wp0[0], wp0[1]);
    const short8 b1 = pack8(wp1[0], wp1[1]);
    f32x4 z = (f32x4){0.f, 0.f, 0.f, 0.f};
    z = __builtin_amdgcn_mfma_f32_16x16x32_bf16(a0, b0, z, 0, 0, 0);
    z = __builtin_amdgcn_mfma_f32_16x16x32_bf16(a1, b1, z, 0, 0, 0);
    acc[nt] = z;
  }

  if (mode != 2) {
#pragma unroll
    for (int nt = 0; nt < 4; ++nt)
#pragma unroll
      for (int r = 0; r < 4; ++r)
        ot[wave * 16 + quad * 4 + r][nt * 16 + m16] = f2bf(acc[nt][r] * scale);
  } else {
    // transposed + sigma'-permuted: ot[d][sigma'(key)],
    // key = wave*16 + quad*4 + r -> sigma' = quad*8 + (wave&1)*4 + r + (wave>>1)*32
#pragma unroll
    for (int nt = 0; nt < 4; ++nt)
#pragma unroll
      for (int r = 0; r < 4; ++r)
        ot[nt * 16 + m16][quad * 8 + (wave & 1) * 4 + r + (wave >> 1) * 32] =
            f2bf(acc[nt][r]);
  }
  __syncthreads();

  const int orow = tid >> 2, opart = tid & 3;
  if (mode != 2) {
    short* dst = (mode == 0 ? Qp : Kp) + (r0 + orow) * 64 + opart * 16;
    *(short8*)&dst[0] = *(const short8*)&ot[orow][opart * 16];
    *(short8*)&dst[8] = *(const short8*)&ot[orow][opart * 16 + 8];
  } else {
    const int bh = r0 >> 11, s0 = r0 & 2047;
    short* dst = Vtp + bh * 131072 + orow * 2048 + s0 + opart * 16;
    *(short8*)&dst[0] = *(const short8*)&ot[orow][opart * 16];
    *(short8*)&dst[8] = *(const short8*)&ot[orow][opart * 16 + 8];
  }
}

// =============== flash64r: 64 q-rows, in-register P via swapped QK^T ===============
// r15: removes the P LDS round-trip that r12/r13/r14 all carried (75-77 us plateau
// across three structures -> the per-tile serial chain QK->exp->dsW->dsR->PV was the
// invariant limiter). mfma(kb, aq) (operands swapped) gives lane C[key=grp*16+quad*4+r]
// [q=m16]: each lane's 16 p-values land in its OWN quad's A-frag slots for PV, with V
// stored under sigma'(grp*16+qk*4+r)=qk*8+(grp&1)*4+r+(grp>>1)*32 (prep mode-2) and the
// mask table bit-reordered to match. P never touches LDS: -4 ds_write/-2 ds_read per
// tile, no P barrier, l is a per-lane scalar (q=m16). Structure = r12's proven shape:
// 4 waves x 16q, 2 barriers/tile, glds16 double-buffer, counted vmcnt (T4): steady
// vmcnt(5)/(5) [ledger: {M(kk),S(2kk),S(2kk+1),M(kk+1)} = 10 outstanding at waitA],
// peel (4)/(0). LDS = 4*8K (K/V dbuf) + 8K (pt, epilogue only) = 40960 -> 4 blocks/CU.
__global__ __launch_bounds__(256) void flash64r(const short* __restrict__ Qp,
                                                const short* __restrict__ Kp,
                                                const short* __restrict__ Vt,
                                                const unsigned* __restrict__ mmod,
                                                short* __restrict__ Ob) {
  __shared__ __attribute__((aligned(16))) short kt0[4096];
  __shared__ __attribute__((aligned(16))) short kt1[4096];
  __shared__ __attribute__((aligned(16))) short vt0[4096];
  __shared__ __attribute__((aligned(16))) short vt1[4096];
  __shared__ __attribute__((aligned(16))) short pt[4096];  // epilogue staging only
  const int tid = threadIdx.x;
  const int bid = blockIdx.x;
  const int local = bid >> 3;  // XCD-grouping on bid&7
  const int qblk = local & 31;
  const int bh = (bid & 7) * 4 + (local >> 5);
  const int q0 = qblk << 6;
  const int b = bh >> 4;
  const short* Qh = Qp + bh * 131072;
  const short* Kh = Kp + bh * 131072;
  const short* Vh = Vt + bh * 131072;
  const int lane = tid & 63, wave = tid >> 6;
  const int m16 = lane & 15, quad = lane >> 4;
  const int srow = lane >> 3, sj = (lane & 7) ^ srow;
  const int koff = m16 * 128 + ((quad ^ (m16 & 7)) * 16);
  // per-lane mask dword: table tid' = wave*64 + quad*16 + m16, one dword per kp (2 tiles)
  const unsigned* mq = mmod + ((b * 32 + qblk) * 16) * 256 + wave * 64 + quad * 16 + m16;

  char* const ptB = (char*)pt;

  short8 aq[2];
#pragma unroll
  for (int h = 0; h < 2; ++h)
    aq[h] = *(const short8*)&Qh[(q0 + wave * 16 + m16) * 64 + h * 32 + quad * 8];

  float l = 0.f;
  f32x4 oacc[4];
#pragma unroll
  for (int dt = 0; dt < 4; ++dt) oacc[dt] = (f32x4){0.f, 0.f, 0.f, 0.f};

  // stage 64-key tile ka into (ktb, vtb); 4 glds16 per wave (+4 vmcnt)
  auto stage = [&](short* ktb, short* vtb, int ka) {
#pragma unroll
    for (int t = 0; t < 2; ++t) {
      const int crow = wave * 16 + t * 8;
      glds16(Kh + (ka * 64 + crow + srow) * 64 + sj * 8, ktb + crow * 64, lane);
      glds16(Vh + (crow + srow) * 2048 + ka * 64 + sj * 8, vtb + crow * 64, lane);
    }
  };

  // full tile: swapped QK^T -> in-register P -> PV. No LDS writes.
  auto compute = [&](const short* ktp, const short* vtp, unsigned mw, int bb) {
    const char* ktb = (const char*)ktp;
    const char* vtb = (const char*)vtp;
    // S^T quadrants: s[grp][r] = S[q = m16][key = grp*16 + quad*4 + r]
    f32x4 s[4];
    __builtin_amdgcn_s_setprio(1);
#pragma unroll
    for (int grp = 0; grp < 4; ++grp) {
      const int o0 = grp * 2048 + koff;
      const short8 kb0 = *(const short8*)(ktb + o0);
      const short8 kb1 = *(const short8*)(ktb + (o0 ^ 64));
      f32x4 z = (f32x4){0.f, 0.f, 0.f, 0.f};
      z = __builtin_amdgcn_mfma_f32_16x16x32_bf16(kb0, aq[0], z, 0, 0, 0);
      z = __builtin_amdgcn_mfma_f32_16x16x32_bf16(kb1, aq[1], z, 0, 0, 0);
      s[grp] = z;
    }
    __builtin_amdgcn_s_setprio(0);

    // p = exp2(s) & mask-bit; per-lane l (all 16 p's belong to q = m16)
    float p[4][4];
#pragma unroll
    for (int grp = 0; grp < 4; ++grp)
#pragma unroll
      for (int r = 0; r < 4; ++r)
        p[grp][r] = fand(fexp2(s[grp][r]), bmask(mw, bb + grp * 4 + r));
    float g0 = (p[0][0] + p[0][1]) + (p[0][2] + p[0][3]);
    float g1 = (p[1][0] + p[1][1]) + (p[1][2] + p[1][3]);
    float g2 = (p[2][0] + p[2][1]) + (p[2][2] + p[2][3]);
    float g3 = (p[3][0] + p[3][1]) + (p[3][2] + p[3][3]);
    l += (g0 + g1) + (g2 + g3);

    // pack P into the PV A-fragments directly (sigma' makes these the lane's slots):
    // ap0 shorts = [p0r0..p0r3, p1r0..p1r3], ap1 = [p2..., p3...]
    int4v t0, t1;
    t0.x = pktr(p[0][0], p[0][1]);
    t0.y = pktr(p[0][2], p[0][3]);
    t0.z = pktr(p[1][0], p[1][1]);
    t0.w = pktr(p[1][2], p[1][3]);
    t1.x = pktr(p[2][0], p[2][1]);
    t1.y = pktr(p[2][2], p[2][3]);
    t1.z = pktr(p[3][0], p[3][1]);
    t1.w = pktr(p[3][2], p[3][3]);
    const short8 ap0 = __builtin_bit_cast(short8, t0);
    const short8 ap1 = __builtin_bit_cast(short8, t1);

    // O += P V
    __builtin_amdgcn_s_setprio(1);
#pragma unroll
    for (int dt = 0; dt < 4; ++dt) {
      const int o0 = dt * 2048 + koff;
      const short8 vb0 = *(const short8*)(vtb + o0);
      const short8 vb1 = *(const short8*)(vtb + (o0 ^ 64));
      f32x4 z = oacc[dt];
      z = __builtin_amdgcn_mfma_f32_16x16x32_bf16(ap0, vb0, z, 0, 0, 0);
      z = __builtin_amdgcn_mfma_f32_16x16x32_bf16(ap1, vb1, z, 0, 0, 0);
      oacc[dt] = z;
    }
    __builtin_amdgcn_s_setprio(0);
  };

  // ---- prologue: mask for kp=0, both stages; first waitA covers aq+M0+S0 ----
  unsigned mw = mq[0];
  stage(kt0, vt0, 0);
  stage(kt1, vt1, 1);

  for (int kk = 0; kk < 15; ++kk) {
    const unsigned mwn = mq[(kk + 1) * 256];
    // tile A = 2kk (buf0): drain M(kk)+S(2kk); newer = S(2kk+1)[4] + M(kk+1)[1]
    asm volatile("s_waitcnt vmcnt(5)" ::: "memory");
    __builtin_amdgcn_s_barrier();
    compute(kt0, vt0, mw, 0);
    __builtin_amdgcn_s_barrier();  // done reading buf0
    stage(kt0, vt0, 2 * kk + 2);
    // tile B = 2kk+1 (buf1): drain S(2kk+1); newer = M(kk+1)[1] + S(2kk+2)[4]
    asm volatile("s_waitcnt vmcnt(5)" ::: "memory");
    __builtin_amdgcn_s_barrier();
    compute(kt1, vt1, mw, 16);
    __builtin_amdgcn_s_barrier();  // done reading buf1
    stage(kt1, vt1, 2 * kk + 3);
    mw = mwn;
  }
  // peeled kk=15: outstanding [M15(1), S30(4), S31(4)]
  asm volatile("s_waitcnt vmcnt(4)" ::: "memory");
  __builtin_amdgcn_s_barrier();
  compute(kt0, vt0, mw, 0);
  asm volatile("s_waitcnt vmcnt(0)" ::: "memory");
  __builtin_amdgcn_s_barrier();
  compute(kt1, vt1, mw, 16);

  // ---- epilogue ----
  // l total per q = m16: reduce across the 4 quads
  l += __shfl_xor(l, 16);
  l += __shfl_xor(l, 32);
  // oacc rows are q = quad*4 + r -> fetch matching l via shuffle from lane quad*4+r
  float linv[4];
#pragma unroll
  for (int r = 0; r < 4; ++r) linv[r] = 1.0f / __shfl(l, quad * 4 + r, 64);

  // normalize, write O (bf16) into pt (swizzled, wave-private rows)
#pragma unroll
  for (int r = 0; r < 4; ++r) {
    const int row = wave * 16 + quad * 4 + r;
#pragma unroll
    for (int dt = 0; dt < 4; ++dt)
      *(short*)(ptB + row * 128 + ((dt * 32 + m16 * 2) ^ ((row & 7) << 4))) =
          f2bf(oacc[dt][r] * linv[r]);
  }
  asm volatile("s_waitcnt lgkmcnt(0)" ::: "memory");  // same-wave rows: no barrier

  // coalesced O store (rows partitioned within the wave)
  const int orow = lane >> 2, opart = lane & 3;
  const int prow = wave * 16 + orow;
  const int oswz = (orow & 7) << 4;
  short* og = Ob + (bh * 2048 + q0 + prow) * 64 + opart * 16;
  *(short8*)&og[0] = *(const short8*)(ptB + prow * 128 + ((opart * 32) ^ oswz));
  *(short8*)&og[8] = *(const short8*)(ptB + prow * 128 + ((opart * 32 + 16) ^ oswz));
}

// =============== final projection: out = Ob @ Wo^T + bo, 64x128 tiles ===============
__global__ __launch_bounds__(256) void outproj(const short* __restrict__ Ob,
                                               const short* __restrict__ Wob,
                                               const float* __restrict__ bo,
                                               float* __restrict__ out) {
  __shared__ short at[64][72];
  __shared__ short bt[128][72];
  const int tid = threadIdx.x;
  const int bid = blockIdx.x;
  const int ct = bid >> 6, rt = bid & 63;  // ct-major: consecutive bids share Wob slab
  const int r0 = rt * 64, c0 = ct * 128;
  const int lane = tid & 63, wave = tid >> 6;
  const int mr = (wave >> 1) * 32, nc = (wave & 1) * 64;
  const int m16 = lane & 15, quad = lane >> 4;
  const int arow = tid >> 2, apart = tid & 3;
  const int brow = tid >> 1, bhalf = (tid & 1) * 32;

  f32x4 acc[2][4];
#pragma unroll
  for (int mt = 0; mt < 2; ++mt)
#pragma unroll
    for (int nt = 0; nt < 4; ++nt) acc[mt][nt] = (f32x4){0.f, 0.f, 0.f, 0.f};

  for (int kc = 0; kc < 16; ++kc) {
    __syncthreads();
    const short* ag = &Ob[(r0 + arow) * 1024 + kc * 64 + apart * 16];
    const short* bg = &Wob[(c0 + brow) * 1024 + kc * 64 + bhalf];
    *(short8*)&at[arow][apart * 16] = *(const short8*)&ag[0];
    *(short8*)&at[arow][apart * 16 + 8] = *(const short8*)&ag[8];
    *(short8*)&bt[brow][bhalf] = *(const short8*)&bg[0];
    *(short8*)&bt[brow][bhalf + 8] = *(const short8*)&bg[8];
    *(short8*)&bt[brow][bhalf + 16] = *(const short8*)&bg[16];
    *(short8*)&bt[brow][bhalf + 24] = *(const short8*)&bg[24];
    __syncthreads();

#pragma unroll
    for (int kh = 0; kh < 2; ++kh) {
      short8 af[2], bf[4];
#pragma unroll
      for (int i = 0; i < 2; ++i)
        af[i] = *(const short8*)&at[mr + i * 16 + m16][kh * 32 + quad * 8];
#pragma unroll
      for (int j = 0; j < 4; ++j)
        bf[j] = *(const short8*)&bt[nc + j * 16 + m16][kh * 32 + quad * 8];
#pragma unroll
      for (int mt = 0; mt < 2; ++mt)
#pragma unroll
        for (int nt = 0; nt < 4; ++nt)
          acc[mt][nt] = __builtin_amdgcn_mfma_f32_16x16x32_bf16(af[mt], bf[nt], acc[mt][nt], 0, 0, 0);
    }
  }

#pragma unroll
  for (int nt = 0; nt < 4; ++nt) {
    const int col = c0 + nc + nt * 16 + m16;
    const float bias = bo[col];
#pragma unroll
    for (int mt = 0; mt < 2; ++mt)
#pragma unroll
      for (int rr2 = 0; rr2 < 4; ++rr2)
        out[(r0 + mr + mt * 16 + quad * 4 + rr2) * 1024 + col] = acc[mt][nt][rr2] + bias;
  }
}

// ---------------- launch ----------------
extern "C" void kernel_launch(void* const* d_in, const int* in_sizes, int n_in,
                              void* d_out, int out_size, void* d_ws, size_t ws_size,
                              hipStream_t stream) {
  const float* query = (const float*)d_in[0];
  const float* key = (const float*)d_in[1];
  const float* value = (const float*)d_in[2];
  const int* mask = (const int*)d_in[3];
  const float* Wq = (const float*)d_in[4];
  const float* Wk = (const float*)d_in[5];
  const float* Wv = (const float*)d_in[6];
  const float* Wo = (const float*)d_in[7];
  const float* bo = (const float*)d_in[8];
  float* out = (float*)d_out;

  char* ws = (char*)d_ws;
  short* Qp = (short*)(ws);                       // 8 MB
  short* Kp = (short*)(ws + 8388608);             // 8 MB
  short* Vt = (short*)(ws + 16777216);            // 8 MB
  short* Ob = (short*)(ws + 25165824);            // 8 MB (flash output, distinct from Qp)
  short* Wob = (short*)(ws + 41943040);           // 2 MB
  unsigned* mmod = (unsigned*)(ws + 44564480);    // 1 MB

  prep<<<5120, 256, 0, stream>>>(query, key, value, Wq, Wk, Wv, Wo, mask,
                                 Qp, Kp, Vt, Wob, mmod);
  flash64r<<<1024, 256, 0, stream>>>(Qp, Kp, Vt, mmod, Ob);
  outproj<<<512, 256, 0, stream>>>(Ob, Wob, bo, out);
}

// Round 5
// 218.397 us; speedup vs baseline: 1.1275x; 1.0085x over previous
//
#include <hip/hip_runtime.h>

typedef __attribute__((ext_vector_type(8))) short short8;
typedef __attribute__((ext_vector_type(4))) float f32x4;
typedef __attribute__((ext_vector_type(2))) int int2v;
typedef __attribute__((ext_vector_type(4))) int int4v;

__device__ __forceinline__ short f2bf(float f) {
  unsigned u = __builtin_bit_cast(unsigned, f);
  u += 0x7fff + ((u >> 16) & 1);  // RNE
  return (short)(u >> 16);
}

__device__ __forceinline__ int pk2bf(float lo, float hi) {
#if defined(__gfx950__) && __has_builtin(__builtin_amdgcn_cvt_pk_bf16_f32)
  typedef __attribute__((ext_vector_type(2))) __bf16 bf16x2;
  bf16x2 v = __builtin_amdgcn_cvt_pk_bf16_f32(lo, hi);
  return __builtin_bit_cast(int, v);
#else
  return (int)(unsigned short)(short)f2bf(lo) | (((int)f2bf(hi)) << 16);
#endif
}

// truncating pack (cheap; bias cancels through p/l normalization — l now sums
// the SAME truncated p via the ones-MFMA, so O/l is softmax of the used weights)
__device__ __forceinline__ int pktr(float lo, float hi) {
  return (int)(__builtin_bit_cast(unsigned, lo) >> 16) |
         (int)(__builtin_bit_cast(unsigned, hi) & 0xffff0000u);
}

__device__ __forceinline__ short8 pack8(f32x4 a, f32x4 b) {
  int4v t;
  t.x = pk2bf(a[0], a[1]);
  t.y = pk2bf(a[2], a[3]);
  t.z = pk2bf(b[0], b[1]);
  t.w = pk2bf(b[2], b[3]);
  return __builtin_bit_cast(short8, t);
}

__device__ __forceinline__ float fand(float p, int m) {
  return __builtin_bit_cast(float, __builtin_bit_cast(int, p) & m);
}

__device__ __forceinline__ int bmask(unsigned w, int bit) {
#if __has_builtin(__builtin_amdgcn_sbfe)
  return __builtin_amdgcn_sbfe((int)w, bit, 1);  // 0 or -1
#else
  return ((int)(w << (31 - bit))) >> 31;
#endif
}

__device__ __forceinline__ float fexp2(float x) {
#if __has_builtin(__builtin_amdgcn_exp2f)
  return __builtin_amdgcn_exp2f(x);
#else
  return exp2f(x);
#endif
}

// async global->LDS, 16B per lane; LDS dest = wave-uniform base + lane*16
__device__ __forceinline__ void glds16(const short* g, short* lbase, int lane) {
#if __has_builtin(__builtin_amdgcn_global_load_lds)
  __builtin_amdgcn_global_load_lds(
      (const __attribute__((address_space(1))) unsigned int*)g,
      (__attribute__((address_space(3))) unsigned int*)lbase, 16, 0, 0);
#else
  *(short8*)(lbase + lane * 8) = *(const short8*)g;
#endif
}

// =============== prep: projections + Wo cvt + packed mask table ===============
// r15 layout: mask-table bits and V column permutation sigma' match the in-register-P
// flash. sigma'(grp*16 + qk*4 + r) = qk*8 + (grp&1)*4 + r + (grp>>1)*32.
__global__ __launch_bounds__(256) void prep(const float* __restrict__ q,
                                            const float* __restrict__ k,
                                            const float* __restrict__ v,
                                            const float* __restrict__ Wq,
                                            const float* __restrict__ Wk,
                                            const float* __restrict__ Wv,
                                            const float* __restrict__ Wo,
                                            const int* __restrict__ mask,
                                            short* __restrict__ Qp,
                                            short* __restrict__ Kp,
                                            short* __restrict__ Vtp,
                                            short* __restrict__ Wob,
                                            unsigned* __restrict__ mmod) {
  const int bid = blockIdx.x;
  const int tid = threadIdx.x;

  if (bid >= 4096) {  // ---- mask table (in-reg-P layout) ----
    const int mb = bid - 4096;       // (b*32+q64)*16 + kp
    const int kp = mb & 15, bq = mb >> 4;
    const int b_ = bq >> 5, q64 = bq & 31;
    const int wv = tid >> 6, qd = (tid >> 4) & 3, m16_ = tid & 15;
    // bit[hb*16+grp*4+r] = mask[q64*64 + wv*16 + m16_][(kp*2+hb)*64 + grp*16 + qd*4 + r]
    unsigned d = 0;
#pragma unroll
    for (int hb = 0; hb < 2; ++hb) {
      const int* mr = mask + b_ * 4194304 + (q64 * 64 + wv * 16 + m16_) * 2048 +
                      (kp * 2 + hb) * 64 + qd * 4;
#pragma unroll
      for (int grp = 0; grp < 4; ++grp)
#pragma unroll
        for (int r = 0; r < 4; ++r)
          if (mr[grp * 16 + r] != 0) d |= 1u << (hb * 16 + grp * 4 + r);
    }
    mmod[mb * 256 + tid] = d;
    return;
  }
  if (bid >= 3072) {  // ---- Wo convert ----
    const int i = ((bid - 3072) * 256 + tid) * 4;
    const f32x4 x = *(const f32x4*)&Wo[i];
    int2v o;
    o.x = pk2bf(x[0], x[1]);
    o.y = pk2bf(x[2], x[3]);
    *(int2v*)&Wob[i] = o;
    return;
  }

  // ---- projection: Out = X @ W^T on a 64-row slab ----
  __shared__ short xt[64][72];
  __shared__ short ot[64][72];
  const int mode = bid >> 10;
  const int bt = bid & 1023;
  const float* X;
  const float* W;
  float scale;
  if (mode == 0) { X = q; W = Wq; scale = 0.045084220f; }  // log2(e)/32 folded into Q
  else if (mode == 1) { X = k; W = Wk; scale = 1.0f; }
  else { X = v; W = Wv; scale = 1.0f; }

  const int r0 = bt * 64;
  const int row = tid >> 2, seg = (tid & 3) * 16;
  const f32x4* xs = (const f32x4*)(X + (r0 + row) * 64 + seg);
  const f32x4 x0 = xs[0], x1 = xs[1], x2 = xs[2], x3 = xs[3];
  *(short8*)&xt[row][seg] = pack8(x0, x1);
  *(short8*)&xt[row][seg + 8] = pack8(x2, x3);
  __syncthreads();

  const int lane = tid & 63, wave = tid >> 6;
  const int m16 = lane & 15, quad = lane >> 4;

  const short8 a0 = *(const short8*)&xt[wave * 16 + m16][quad * 8];
  const short8 a1 = *(const short8*)&xt[wave * 16 + m16][32 + quad * 8];

  f32x4 acc[4];
#pragma unroll
  for (int nt = 0; nt < 4; ++nt) {
    const f32x4* wp0 = (const f32x4*)&W[(nt * 16 + m16) * 64 + quad * 8];
    const f32x4* wp1 = (const f32x4*)&W[(nt * 16 + m16) * 64 + 32 + quad * 8];
    const short8 b0 = pack8(wp0[0], wp0[1]);
    const short8 b1 = pack8(wp1[0], wp1[1]);
    f32x4 z = (f32x4){0.f, 0.f, 0.f, 0.f};
    z = __builtin_amdgcn_mfma_f32_16x16x32_bf16(a0, b0, z, 0, 0, 0);
    z = __builtin_amdgcn_mfma_f32_16x16x32_bf16(a1, b1, z, 0, 0, 0);
    acc[nt] = z;
  }

  if (mode != 2) {
#pragma unroll
    for (int nt = 0; nt < 4; ++nt)
#pragma unroll
      for (int r = 0; r < 4; ++r)
        ot[wave * 16 + quad * 4 + r][nt * 16 + m16] = f2bf(acc[nt][r] * scale);
  } else {
    // transposed + sigma'-permuted: ot[d][sigma'(key)],
    // key = wave*16 + quad*4 + r -> sigma' = quad*8 + (wave&1)*4 + r + (wave>>1)*32
#pragma unroll
    for (int nt = 0; nt < 4; ++nt)
#pragma unroll
      for (int r = 0; r < 4; ++r)
        ot[nt * 16 + m16][quad * 8 + (wave & 1) * 4 + r + (wave >> 1) * 32] =
            f2bf(acc[nt][r]);
  }
  __syncthreads();

  const int orow = tid >> 2, opart = tid & 3;
  if (mode != 2) {
    short* dst = (mode == 0 ? Qp : Kp) + (r0 + orow) * 64 + opart * 16;
    *(short8*)&dst[0] = *(const short8*)&ot[orow][opart * 16];
    *(short8*)&dst[8] = *(const short8*)&ot[orow][opart * 16 + 8];
  } else {
    const int bh = r0 >> 11, s0 = r0 & 2047;
    short* dst = Vtp + bh * 131072 + orow * 2048 + s0 + opart * 16;
    *(short8*)&dst[0] = *(const short8*)&ot[orow][opart * 16];
    *(short8*)&dst[8] = *(const short8*)&ot[orow][opart * 16 + 8];
  }
}

// =============== flash64r: 64 q-rows, in-register P, l via ones-MFMA ===============
// r16 on top of r15 (63.0 us, MfmaUtil 22, VALUBusy 59):
//  (a) LDS 40960 -> 32768: pt dropped, epilogue reuses kt0 (all kt0 reads end before
//      the barrier preceding the final compute(kt1)). Guarantees >=4 blocks/CU even
//      with allocation-granularity padding (capacity 5) — occupancy counter suggested
//      we may have been at 3 resident + straggler tail.
//  (b) l accumulated on the matrix pipe: 2 extra MFMA/tile against a constant all-ones
//      B-frag give D[q][*] = sum_k P[q][k] in oaccL[r] on EVERY lane (col-independent)
//      -> kills 15 VALU adds/tile/wave and all epilogue l shuffles; l now sums the
//      truncated bf16 p actually used in PV (self-consistent softmax).
// vmcnt ledger unchanged (verified: prologue aq2+M0+S0+S1+M1=12, vmcnt(5) drains
// aq,M0,S0; steady 10->vmcnt(5); peel vmcnt(4)/vmcnt(0)).
__global__ __launch_bounds__(256) void flash64r(const short* __restrict__ Qp,
                                                const short* __restrict__ Kp,
                                                const short* __restrict__ Vt,
                                                const unsigned* __restrict__ mmod,
                                                short* __restrict__ Ob) {
  __shared__ __attribute__((aligned(16))) short kt0[4096];
  __shared__ __attribute__((aligned(16))) short kt1[4096];
  __shared__ __attribute__((aligned(16))) short vt0[4096];
  __shared__ __attribute__((aligned(16))) short vt1[4096];
  const int tid = threadIdx.x;
  const int bid = blockIdx.x;
  const int local = bid >> 3;  // XCD-grouping on bid&7
  const int qblk = local & 31;
  const int bh = (bid & 7) * 4 + (local >> 5);
  const int q0 = qblk << 6;
  const int b = bh >> 4;
  const short* Qh = Qp + bh * 131072;
  const short* Kh = Kp + bh * 131072;
  const short* Vh = Vt + bh * 131072;
  const int lane = tid & 63, wave = tid >> 6;
  const int m16 = lane & 15, quad = lane >> 4;
  const int srow = lane >> 3, sj = (lane & 7) ^ srow;
  const int koff = m16 * 128 + ((quad ^ (m16 & 7)) * 16);
  // per-lane mask dword: table tid' = wave*64 + quad*16 + m16, one dword per kp (2 tiles)
  const unsigned* mq = mmod + ((b * 32 + qblk) * 16) * 256 + wave * 64 + quad * 16 + m16;

  const short onebf = (short)0x3F80;  // bf16 1.0
  const short8 ones = (short8){onebf, onebf, onebf, onebf, onebf, onebf, onebf, onebf};

  short8 aq[2];
#pragma unroll
  for (int h = 0; h < 2; ++h)
    aq[h] = *(const short8*)&Qh[(q0 + wave * 16 + m16) * 64 + h * 32 + quad * 8];

  f32x4 oaccL = (f32x4){0.f, 0.f, 0.f, 0.f};  // row-sum accumulator (l)
  f32x4 oacc[4];
#pragma unroll
  for (int dt = 0; dt < 4; ++dt) oacc[dt] = (f32x4){0.f, 0.f, 0.f, 0.f};

  // stage 64-key tile ka into (ktb, vtb); 4 glds16 per wave (+4 vmcnt)
  auto stage = [&](short* ktb, short* vtb, int ka) {
#pragma unroll
    for (int t = 0; t < 2; ++t) {
      const int crow = wave * 16 + t * 8;
      glds16(Kh + (ka * 64 + crow + srow) * 64 + sj * 8, ktb + crow * 64, lane);
      glds16(Vh + (crow + srow) * 2048 + ka * 64 + sj * 8, vtb + crow * 64, lane);
    }
  };

  // full tile: swapped QK^T -> in-register P -> PV (+ l via ones-MFMA). No LDS writes.
  auto compute = [&](const short* ktp, const short* vtp, unsigned mw, int bb) {
    const char* ktb = (const char*)ktp;
    const char* vtb = (const char*)vtp;
    // S^T quadrants: s[grp][r] = S[q = m16][key = grp*16 + quad*4 + r]
    f32x4 s[4];
    __builtin_amdgcn_s_setprio(1);
#pragma unroll
    for (int grp = 0; grp < 4; ++grp) {
      const int o0 = grp * 2048 + koff;
      const short8 kb0 = *(const short8*)(ktb + o0);
      const short8 kb1 = *(const short8*)(ktb + (o0 ^ 64));
      f32x4 z = (f32x4){0.f, 0.f, 0.f, 0.f};
      z = __builtin_amdgcn_mfma_f32_16x16x32_bf16(kb0, aq[0], z, 0, 0, 0);
      z = __builtin_amdgcn_mfma_f32_16x16x32_bf16(kb1, aq[1], z, 0, 0, 0);
      s[grp] = z;
    }
    __builtin_amdgcn_s_setprio(0);

    // p = exp2(s) & mask-bit (all 16 p's belong to q = m16)
    float p[4][4];
#pragma unroll
    for (int grp = 0; grp < 4; ++grp)
#pragma unroll
      for (int r = 0; r < 4; ++r)
        p[grp][r] = fand(fexp2(s[grp][r]), bmask(mw, bb + grp * 4 + r));

    // pack P into the PV A-fragments directly (sigma' makes these the lane's slots)
    int4v t0, t1;
    t0.x = pktr(p[0][0], p[0][1]);
    t0.y = pktr(p[0][2], p[0][3]);
    t0.z = pktr(p[1][0], p[1][1]);
    t0.w = pktr(p[1][2], p[1][3]);
    t1.x = pktr(p[2][0], p[2][1]);
    t1.y = pktr(p[2][2], p[2][3]);
    t1.z = pktr(p[3][0], p[3][1]);
    t1.w = pktr(p[3][2], p[3][3]);
    const short8 ap0 = __builtin_bit_cast(short8, t0);
    const short8 ap1 = __builtin_bit_cast(short8, t1);

    // O += P V; l += P·1 (matrix pipe; no LDS dep -> issues while vb reads land)
    __builtin_amdgcn_s_setprio(1);
    oaccL = __builtin_amdgcn_mfma_f32_16x16x32_bf16(ap0, ones, oaccL, 0, 0, 0);
    oaccL = __builtin_amdgcn_mfma_f32_16x16x32_bf16(ap1, ones, oaccL, 0, 0, 0);
#pragma unroll
    for (int dt = 0; dt < 4; ++dt) {
      const int o0 = dt * 2048 + koff;
      const short8 vb0 = *(const short8*)(vtb + o0);
      const short8 vb1 = *(const short8*)(vtb + (o0 ^ 64));
      f32x4 z = oacc[dt];
      z = __builtin_amdgcn_mfma_f32_16x16x32_bf16(ap0, vb0, z, 0, 0, 0);
      z = __builtin_amdgcn_mfma_f32_16x16x32_bf16(ap1, vb1, z, 0, 0, 0);
      oacc[dt] = z;
    }
    __builtin_amdgcn_s_setprio(0);
  };

  // ---- prologue: mask for kp=0, both stages; first waitA covers aq+M0+S0 ----
  unsigned mw = mq[0];
  stage(kt0, vt0, 0);
  stage(kt1, vt1, 1);

  for (int kk = 0; kk < 15; ++kk) {
    const unsigned mwn = mq[(kk + 1) * 256];
    // tile A = 2kk (buf0): drain M(kk)+S(2kk); newer = S(2kk+1)[4] + M(kk+1)[1]
    asm volatile("s_waitcnt vmcnt(5)" ::: "memory");
    __builtin_amdgcn_s_barrier();
    compute(kt0, vt0, mw, 0);
    __builtin_amdgcn_s_barrier();  // done reading buf0
    stage(kt0, vt0, 2 * kk + 2);
    // tile B = 2kk+1 (buf1): drain S(2kk+1); newer = M(kk+1)[1] + S(2kk+2)[4]
    asm volatile("s_waitcnt vmcnt(5)" ::: "memory");
    __builtin_amdgcn_s_barrier();
    compute(kt1, vt1, mw, 16);
    __builtin_amdgcn_s_barrier();  // done reading buf1
    stage(kt1, vt1, 2 * kk + 3);
    mw = mwn;
  }
  // peeled kk=15: outstanding [M15(1), S30(4), S31(4)]
  asm volatile("s_waitcnt vmcnt(4)" ::: "memory");
  __builtin_amdgcn_s_barrier();
  compute(kt0, vt0, mw, 0);
  asm volatile("s_waitcnt vmcnt(0)" ::: "memory");
  __builtin_amdgcn_s_barrier();
  compute(kt1, vt1, mw, 16);

  // ---- epilogue ----
  // l[q = quad*4 + r] = oaccL[r] on every lane (ones-B makes all 16 cols equal)
  float linv[4];
#pragma unroll
  for (int r = 0; r < 4; ++r) linv[r] = 1.0f / oaccL[r];

  // normalize, write O (bf16) into kt0 (swizzled; wave-private rows — safe: all
  // cross-wave kt0 reads finished before the barrier preceding compute(kt1))
  char* const ptB = (char*)kt0;
#pragma unroll
  for (int r = 0; r < 4; ++r) {
    const int row = wave * 16 + quad * 4 + r;
#pragma unroll
    for (int dt = 0; dt < 4; ++dt)
      *(short*)(ptB + row * 128 + ((dt * 32 + m16 * 2) ^ ((row & 7) << 4))) =
          f2bf(oacc[dt][r] * linv[r]);
  }
  asm volatile("s_waitcnt lgkmcnt(0)" ::: "memory");  // same-wave rows: no barrier

  // coalesced O store (rows partitioned within the wave)
  const int orow = lane >> 2, opart = lane & 3;
  const int prow = wave * 16 + orow;
  const int oswz = (orow & 7) << 4;
  short* og = Ob + (bh * 2048 + q0 + prow) * 64 + opart * 16;
  *(short8*)&og[0] = *(const short8*)(ptB + prow * 128 + ((opart * 32) ^ oswz));
  *(short8*)&og[8] = *(const short8*)(ptB + prow * 128 + ((opart * 32 + 16) ^ oswz));
}

// =============== outproj: out = Ob @ Wo^T + bo, 64x128 tiles, pipelined ===============
// r16: flash-pattern port — glds16 staging into linear LDS with the proven
// row-XOR swizzle (LDS[row][slot j] = global[row][j ^ (row&7)], read back with
// slot ^ (m16&7)), double-buffered, counted vmcnt(6) (ledger: prologue 12 in
// flight, steady drain-6, peel 6/0). Replaces the old reg-staged +
// full-__syncthreads-drain loop. LDS = 2*(8K A + 16K B) = 48 KB, 2 blocks/CU.
__global__ __launch_bounds__(256) void outproj(const short* __restrict__ Ob,
                                               const short* __restrict__ Wob,
                                               const float* __restrict__ bo,
                                               float* __restrict__ out) {
  __shared__ __attribute__((aligned(16))) short at0[4096];
  __shared__ __attribute__((aligned(16))) short at1[4096];
  __shared__ __attribute__((aligned(16))) short bt0[8192];
  __shared__ __attribute__((aligned(16))) short bt1[8192];
  const int tid = threadIdx.x;
  const int bid = blockIdx.x;
  const int ct = bid >> 6, rt = bid & 63;  // ct-major: consecutive bids share Wob slab
  const int r0 = rt * 64, c0 = ct * 128;
  const int lane = tid & 63, wave = tid >> 6;
  const int mr = (wave >> 1) * 32, nc = (wave & 1) * 64;
  const int m16 = lane & 15, quad = lane >> 4;
  const int srow = lane >> 3, sj = (lane & 7) ^ srow;
  const int mswz = (m16 & 7) << 4;

  f32x4 acc[2][4];
#pragma unroll
  for (int mt = 0; mt < 2; ++mt)
#pragma unroll
    for (int nt = 0; nt < 4; ++nt) acc[mt][nt] = (f32x4){0.f, 0.f, 0.f, 0.f};

  // stage one K-slab (64 cols) of A (64 rows) + B (128 rows): 6 glds16/wave
  auto stageK = [&](short* atb, short* btb, int kc) {
#pragma unroll
    for (int t = 0; t < 2; ++t) {
      const int crow = wave * 16 + t * 8;
      glds16(Ob + (r0 + crow + srow) * 1024 + kc * 64 + sj * 8, atb + crow * 64, lane);
    }
#pragma unroll
    for (int t = 0; t < 4; ++t) {
      const int crow = wave * 32 + t * 8;
      glds16(Wob + (c0 + crow + srow) * 1024 + kc * 64 + sj * 8, btb + crow * 64, lane);
    }
  };

  auto computeK = [&](const short* atp, const short* btp) {
    const char* atB = (const char*)atp;
    const char* btB = (const char*)btp;
#pragma unroll
    for (int kh = 0; kh < 2; ++kh) {
      short8 af[2], bf[4];
#pragma unroll
      for (int i = 0; i < 2; ++i)
        af[i] = *(const short8*)(atB + (mr + i * 16 + m16) * 128 +
                                 ((kh * 64 + quad * 16) ^ mswz));
#pragma unroll
      for (int j = 0; j < 4; ++j)
        bf[j] = *(const short8*)(btB + (nc + j * 16 + m16) * 128 +
                                 ((kh * 64 + quad * 16) ^ mswz));
      __builtin_amdgcn_s_setprio(1);
#pragma unroll
      for (int mt = 0; mt < 2; ++mt)
#pragma unroll
        for (int nt = 0; nt < 4; ++nt)
          acc[mt][nt] = __builtin_amdgcn_mfma_f32_16x16x32_bf16(af[mt], bf[nt],
                                                                acc[mt][nt], 0, 0, 0);
      __builtin_amdgcn_s_setprio(0);
    }
  };

  stageK(at0, bt0, 0);
  stageK(at1, bt1, 1);
  for (int kc = 0; kc < 14; ++kc) {
    short* atb = (kc & 1) ? at1 : at0;
    short* btb = (kc & 1) ? bt1 : bt0;
    asm volatile("s_waitcnt vmcnt(6)" ::: "memory");  // drain S(kc), keep S(kc+1)
    __builtin_amdgcn_s_barrier();
    computeK(atb, btb);
    __builtin_amdgcn_s_barrier();  // done reading this buffer
    stageK(atb, btb, kc + 2);
  }
  // peel kc=14, 15: in flight [S14(6), S15(6)]
  asm volatile("s_waitcnt vmcnt(6)" ::: "memory");
  __builtin_amdgcn_s_barrier();
  computeK(at0, bt0);
  asm volatile("s_waitcnt vmcnt(0)" ::: "memory");
  __builtin_amdgcn_s_barrier();
  computeK(at1, bt1);

#pragma unroll
  for (int nt = 0; nt < 4; ++nt) {
    const int col = c0 + nc + nt * 16 + m16;
    const float bias = bo[col];
#pragma unroll
    for (int mt = 0; mt < 2; ++mt)
#pragma unroll
      for (int rr2 = 0; rr2 < 4; ++rr2)
        out[(r0 + mr + mt * 16 + quad * 4 + rr2) * 1024 + col] = acc[mt][nt][rr2] + bias;
  }
}

// ---------------- launch ----------------
extern "C" void kernel_launch(void* const* d_in, const int* in_sizes, int n_in,
                              void* d_out, int out_size, void* d_ws, size_t ws_size,
                              hipStream_t stream) {
  const float* query = (const float*)d_in[0];
  const float* key = (const float*)d_in[1];
  const float* value = (const float*)d_in[2];
  const int* mask = (const int*)d_in[3];
  const float* Wq = (const float*)d_in[4];
  const float* Wk = (const float*)d_in[5];
  const float* Wv = (const float*)d_in[6];
  const float* Wo = (const float*)d_in[7];
  const float* bo = (const float*)d_in[8];
  float* out = (float*)d_out;

  char* ws = (char*)d_ws;
  short* Qp = (short*)(ws);                       // 8 MB
  short* Kp = (short*)(ws + 8388608);             // 8 MB
  short* Vt = (short*)(ws + 16777216);            // 8 MB
  short* Ob = (short*)(ws + 25165824);            // 8 MB (flash output, distinct from Qp)
  short* Wob = (short*)(ws + 41943040);           // 2 MB
  unsigned* mmod = (unsigned*)(ws + 44564480);    // 1 MB

  prep<<<5120, 256, 0, stream>>>(query, key, value, Wq, Wk, Wv, Wo, mask,
                                 Qp, Kp, Vt, Wob, mmod);
  flash64r<<<1024, 256, 0, stream>>>(Qp, Kp, Vt, mmod, Ob);
  outproj<<<512, 256, 0, stream>>>(Ob, Wob, bo, out);
}